// Round 10
// baseline (707.855 us; speedup 1.0000x reference)
//
#include <hip/hip_runtime.h>
#include <cmath>

#define N_   8
#define H_   56
#define W_   56
#define C_   256
#define HW_  3136
#define NHW_ 25088
#define G_   8
#define GC_  32
#define P_   9
#define HID_ 1024
#define XP_H 58
#define XP_W 58

typedef __attribute__((ext_vector_type(8))) short bf16x8;
typedef __attribute__((ext_vector_type(4))) float f32x4;

#define GLOAD_LDS16(g, l) __builtin_amdgcn_global_load_lds( \
    (const __attribute__((address_space(1))) void*)(g), \
    (__attribute__((address_space(3))) void*)(l), 16, 0, 0)

__device__ __forceinline__ unsigned short f2bf(float f) {
    unsigned u = __float_as_uint(f);
    u += 0x7FFF + ((u >> 16) & 1);   // round-to-nearest-even
    return (unsigned short)(u >> 16);
}

__device__ __forceinline__ float bf2f(unsigned short u) {
    return __uint_as_float((unsigned)u << 16);
}

__device__ __forceinline__ float gelu_exact(float v) {
    return 0.5f * v * (1.f + erff(v * 0.70710678118654752f));
}

// ---------------- block-wide sum of (a,b) over 256 threads ----------------
__device__ __forceinline__ float2 block_sum2(float a, float b, float* sm) {
    int lane = threadIdx.x & 63;
    int wid  = threadIdx.x >> 6;
#pragma unroll
    for (int off = 32; off > 0; off >>= 1) {
        a += __shfl_down(a, off, 64);
        b += __shfl_down(b, off, 64);
    }
    if (lane == 0) { sm[wid] = a; sm[wid + 4] = b; }
    __syncthreads();
    float ra = sm[0] + sm[1] + sm[2] + sm[3];
    float rb = sm[4] + sm[5] + sm[6] + sm[7];
    __syncthreads();
    return make_float2(ra, rb);
}

// ---------------- x (NCHW fp32) -> xpad (N,58,58,256 bf16), border pre-zeroed ----------------
__global__ __launch_bounds__(256) void k_prep_xpad(const float* __restrict__ x, unsigned short* __restrict__ xpad) {
    int nh = blockIdx.x;                   // N_*H_ = 448
    int n = nh / H_, h = nh - n * H_;
    int c = threadIdx.x;
    const float* xr = x + ((size_t)(n * C_ + c)) * HW_ + h * W_;
    unsigned short* orow = xpad + ((size_t)((n * XP_H + h + 1) * XP_W + 1)) * C_ + c;
    for (int w = 0; w < W_; ++w) orow[(size_t)w * C_] = f2bf(xr[w]);
}

// ---------------- conv1 weights [co][ci][3][3] -> wTT [kk][co][ci] bf16 ----------------
__global__ __launch_bounds__(256) void k_prep_wTT(const float* __restrict__ w, unsigned short* __restrict__ wTT) {
    int i  = blockIdx.x * 256 + threadIdx.x;   // 9*256*256
    int ci = i & 255;
    int r  = i >> 8;
    int co = r & 255;
    int kk = r >> 8;
    wTT[i] = f2bf(w[(co * 256 + ci) * 9 + kk]);
}

// ---------------- square 256x256 weight -> W^T bf16 [n][k] ----------------
__global__ __launch_bounds__(256) void k_prep_sqT(const float* __restrict__ src, unsigned short* __restrict__ dst) {
    int n = blockIdx.x, k = threadIdx.x;
    dst[n * C_ + k] = f2bf(src[k * C_ + n]);
}

// ---------------- fc1 [256][1024] -> [1024][256] bf16 ----------------
__global__ __launch_bounds__(256) void k_prep_fc1T(const float* __restrict__ src, unsigned short* __restrict__ dst) {
    int n = blockIdx.x, k = threadIdx.x;
    dst[(size_t)n * C_ + k] = f2bf(src[(size_t)k * HID_ + n]);
}

// ---------------- fc2 [1024][256] -> [256][1024] bf16 ----------------
__global__ __launch_bounds__(256) void k_prep_fc2T(const float* __restrict__ src, unsigned short* __restrict__ dst) {
    int n = blockIdx.x, k0 = threadIdx.x;
#pragma unroll
    for (int q = 0; q < 4; ++q) {
        int k = q * 256 + k0;
        dst[(size_t)n * HID_ + k] = f2bf(src[(size_t)k * C_ + n]);
    }
}

// ---------------- offw[256][144] + mskw[256][72] -> omT [256][256] bf16 (+ omb) ----------------
__global__ __launch_bounds__(256) void k_prep_om(const float* __restrict__ offw, const float* __restrict__ offb,
                                                 const float* __restrict__ mskw, const float* __restrict__ mskb,
                                                 unsigned short* __restrict__ omT, float* __restrict__ omb) {
    int n = blockIdx.x, k = threadIdx.x;
    float v = 0.f;
    if (n < 144)      v = offw[k * 144 + n];
    else if (n < 216) v = mskw[k * 72 + (n - 144)];
    omT[n * C_ + k] = f2bf(v);
    if (k == 0) omb[n] = (n < 144) ? offb[n] : (n < 216 ? mskb[n - 144] : 0.f);
}

// ---------------- conv1 implicit GEMM: 128x128 tile, BK=32 (m97 proportions), dbuf + swizzle ----------------
// K = 9 taps x 256; kt = tap*8 + ktk (72 steps). Per wave/iter: 4 gload_lds, 8 ds_read_b128, 16 MFMA.
__global__ __launch_bounds__(256) void k_conv1_mfma(const unsigned short* __restrict__ xpad,
                                                    const unsigned short* __restrict__ wTT,
                                                    const float* __restrict__ g, const float* __restrict__ b,
                                                    const float* __restrict__ m, const float* __restrict__ v,
                                                    float* __restrict__ t, unsigned short* __restrict__ t_bf) {
    __shared__ __align__(16) unsigned char smem[32768];   // 2 x (A 8KB + B 8KB)
    unsigned short* sm16 = (unsigned short*)smem;
    int tid = threadIdx.x;
    int wave = tid >> 6, lane = tid & 63;
    int r = lane & 15, kq = lane >> 4;
    int bid = blockIdx.x;                    // 392 = 8 * 49
    int swz = (bid & 7) * 49 + (bid >> 3);   // bijective XCD-band swizzle
    int mt = swz >> 1, nt = swz & 1;
    int m0 = mt * 128, n0 = nt * 128;
    int wm = wave & 1, wn = wave >> 1;

    // per-lane A-row bases for this wave's two A chunks (q = wave*2 + i)
    size_t abase[2];
#pragma unroll
    for (int i = 0; i < 2; ++i) {
        int pix = m0 + (wave * 2 + i) * 16 + r;
        int n = pix / HW_, hw = pix - n * HW_;
        int h = hw / W_, w = hw - h * W_;
        abase[i] = ((size_t)((n * XP_H + h) * XP_W + w)) * C_ + kq * 8;
    }

    f32x4 acc[4][4] = {};

    auto stage = [&](int kt, int buf) {
        int tap = kt >> 3, ktk = kt & 7;
        int kh = tap / 3, kw = tap - kh * 3;
        int k0 = ktk * 32;
        unsigned short* dstA = sm16 + buf * 8192;
        unsigned short* dstB = dstA + 4096;
        size_t aoff = (size_t)(kh * XP_W + kw) * C_ + k0;
#pragma unroll
        for (int i = 0; i < 2; ++i) {
            int q = wave * 2 + i;
            GLOAD_LDS16(xpad + abase[i] + aoff, dstA + q * 512);
        }
#pragma unroll
        for (int i = 0; i < 2; ++i) {
            int q = wave * 2 + i;
            int nrow = n0 + q * 16 + r;
            GLOAD_LDS16(wTT + ((size_t)(tap * C_) + nrow) * C_ + k0 + kq * 8, dstB + q * 512);
        }
    };

    stage(0, 0);
    int cur = 0;
#pragma unroll 1
    for (int kt = 0; kt < 72; ++kt) {
        if (kt < 71) {
            stage(kt + 1, cur ^ 1);
            asm volatile("s_waitcnt vmcnt(4)" ::: "memory");
        } else {
            asm volatile("s_waitcnt vmcnt(0)" ::: "memory");
        }
        __builtin_amdgcn_s_barrier();
        bf16x8* sA = (bf16x8*)(sm16 + cur * 8192);
        bf16x8* sB = sA + 512;
        bf16x8 af[4], bfr[4];
#pragma unroll
        for (int mi = 0; mi < 4; ++mi) af[mi]  = sA[(wm * 4 + mi) * 64 + lane];
#pragma unroll
        for (int ni = 0; ni < 4; ++ni) bfr[ni] = sB[(wn * 4 + ni) * 64 + lane];
#pragma unroll
        for (int mi = 0; mi < 4; ++mi)
#pragma unroll
            for (int ni = 0; ni < 4; ++ni)
                acc[mi][ni] = __builtin_amdgcn_mfma_f32_16x16x32_bf16(af[mi], bfr[ni], acc[mi][ni], 0, 0, 0);
        __builtin_amdgcn_s_barrier();
        cur ^= 1;
    }

#pragma unroll
    for (int ni = 0; ni < 4; ++ni) {
        int co = n0 + (wn * 4 + ni) * 16 + r;
        float sc = g[co] * rsqrtf(v[co] + 1e-5f);
        float sh = b[co] - m[co] * sc;
#pragma unroll
        for (int mi = 0; mi < 4; ++mi) {
#pragma unroll
            for (int reg = 0; reg < 4; ++reg) {
                int po = m0 + (wm * 4 + mi) * 16 + kq * 4 + reg;
                float val = fmaxf(acc[mi][ni][reg] * sc + sh, 0.f);
                size_t idx = (size_t)po * C_ + co;
                t[idx] = val;
                t_bf[idx] = f2bf(val);
            }
        }
    }
}

// ---------------- input proj: 64x256 staged-dbuf GEMM (K=256) -> xproj_bf (bf16) ----------------
__global__ __launch_bounds__(256) void k_inproj_mfma(const unsigned short* __restrict__ t_bf,
                                                     const unsigned short* __restrict__ inpwT,
                                                     const float* __restrict__ bias,
                                                     unsigned short* __restrict__ xproj_bf) {
    __shared__ __align__(16) unsigned char smem[81920];   // 2 x (A 8KB + B 32KB)
    unsigned short* sm16 = (unsigned short*)smem;
    int tid = threadIdx.x;
    int wave = tid >> 6, lane = tid & 63;
    int r = lane & 15, kq = lane >> 4;
    int m0 = blockIdx.x * 64;

    f32x4 acc[16] = {};

    auto stage = [&](int kt, int buf) {
        int k0 = kt * 64;
        unsigned short* dstA = sm16 + buf * 20480;
        unsigned short* dstB = dstA + 4096;
#pragma unroll
        for (int i = 0; i < 2; ++i) {
            int q = wave * 2 + i;
            int row = m0 + wave * 16 + r;
            GLOAD_LDS16(t_bf + (size_t)row * C_ + k0 + (i * 4 + kq) * 8, dstA + q * 512);
        }
#pragma unroll
        for (int i = 0; i < 8; ++i) {
            int q = wave * 8 + i;
            int nrow = (q >> 1) * 16 + r;
            int cc   = (q & 1) * 4 + kq;
            GLOAD_LDS16(inpwT + (size_t)nrow * C_ + k0 + cc * 8, dstB + q * 512);
        }
    };

    stage(0, 0);
    int cur = 0;
#pragma unroll 1
    for (int kt = 0; kt < 4; ++kt) {
        if (kt < 3) {
            stage(kt + 1, cur ^ 1);
            asm volatile("s_waitcnt vmcnt(10)" ::: "memory");
        } else {
            asm volatile("s_waitcnt vmcnt(0)" ::: "memory");
        }
        __builtin_amdgcn_s_barrier();
        bf16x8* sA = (bf16x8*)(sm16 + cur * 20480);
        bf16x8* sB = sA + 512;
#pragma unroll
        for (int ks = 0; ks < 2; ++ks) {
            bf16x8 a = sA[(wave * 2 + ks) * 64 + lane];
#pragma unroll
            for (int ni = 0; ni < 16; ++ni) {
                bf16x8 b = sB[(ni * 2 + ks) * 64 + lane];
                acc[ni] = __builtin_amdgcn_mfma_f32_16x16x32_bf16(a, b, acc[ni], 0, 0, 0);
            }
        }
        __builtin_amdgcn_s_barrier();
        cur ^= 1;
    }

#pragma unroll
    for (int ni = 0; ni < 16; ++ni) {
        int col = ni * 16 + r;
        float bb = bias[col];
#pragma unroll
        for (int reg = 0; reg < 4; ++reg) {
            int row = m0 + wave * 16 + kq * 4 + reg;
            xproj_bf[(size_t)row * C_ + col] = f2bf(acc[ni][reg] + bb);
        }
    }
}

// ---------------- depthwise 3x3 + LN(1e-6) + exact GELU -> x1_bf (4 pixels/block, bf16 input) ----------------
__global__ __launch_bounds__(256) void k_dw(const unsigned short* __restrict__ t_bf, const float* __restrict__ dww,
                                            const float* __restrict__ dwb, const float* __restrict__ lg,
                                            const float* __restrict__ lb, unsigned short* __restrict__ x1_bf) {
    __shared__ float sm[8];
    int p0 = blockIdx.x * 4;               // NHW_/4 blocks; groups never cross rows (W_%4==0)
    int n = p0 / HW_, hw = p0 - n * HW_;
    int h = hw / W_, w0 = hw - h * W_;
    int c = threadIdx.x;

    float vals[3][6];
#pragma unroll
    for (int dy = 0; dy < 3; ++dy) {
        int y = h + dy - 1;
        bool rowok = (unsigned)y < H_;
#pragma unroll
        for (int dx = 0; dx < 6; ++dx) {
            int xx = w0 + dx - 1;
            bool ok = rowok && ((unsigned)xx < W_);
            vals[dy][dx] = ok ? bf2f(t_bf[((size_t)(n * HW_ + y * W_ + xx)) * C_ + c]) : 0.f;
        }
    }
    float wv[9];
#pragma unroll
    for (int k = 0; k < 9; ++k) wv[k] = dww[k * C_ + c];
    float bias = dwb[c], lgc = lg[c], lbc = lb[c];

#pragma unroll 1
    for (int px = 0; px < 4; ++px) {
        float acc = bias;
#pragma unroll
        for (int kh = 0; kh < 3; ++kh)
#pragma unroll
            for (int kw = 0; kw < 3; ++kw)
                acc = fmaf(vals[kh][px + kw], wv[kh * 3 + kw], acc);
        float2 rr = block_sum2(acc, acc * acc, sm);
        float mu  = rr.x * (1.f / C_);
        float var = fmaxf(rr.y * (1.f / C_) - mu * mu, 0.f);
        float rs  = rsqrtf(var + 1e-6f);
        float val = (acc - mu) * rs * lgc + lbc;
        x1_bf[(size_t)(p0 + px) * C_ + c] = f2bf(gelu_exact(val));
    }
}

// ---------------- offset+mask via MFMA (N=256: 144 off | 72 msk | 40 pad) + softmax ----------------
__global__ __launch_bounds__(256) void k_offmask_mfma(const unsigned short* __restrict__ x1_bf,
                                                      const unsigned short* __restrict__ omT,
                                                      const float* __restrict__ omb,
                                                      float* __restrict__ offo, float* __restrict__ msko) {
    __shared__ float som[32][225];
    int wave = threadIdx.x >> 6, lane = threadIdx.x & 63;
    int r = lane & 15, kq = lane >> 4;
    int p0 = blockIdx.x * 32, co0 = wave * 64;
    f32x4 acc[2][4] = {};
#pragma unroll 1
    for (int ks = 0; ks < 8; ++ks) {
        bf16x8 a0 = *(const bf16x8*)(x1_bf + (size_t)(p0 + r) * C_ + ks * 32 + kq * 8);
        bf16x8 a1 = *(const bf16x8*)(x1_bf + (size_t)(p0 + 16 + r) * C_ + ks * 32 + kq * 8);
        const unsigned short* bp = omT + (size_t)(co0 + r) * C_ + ks * 32 + kq * 8;
#pragma unroll
        for (int ni = 0; ni < 4; ++ni) {
            bf16x8 b = *(const bf16x8*)(bp + (size_t)ni * 16 * C_);
            acc[0][ni] = __builtin_amdgcn_mfma_f32_16x16x32_bf16(a0, b, acc[0][ni], 0, 0, 0);
            acc[1][ni] = __builtin_amdgcn_mfma_f32_16x16x32_bf16(a1, b, acc[1][ni], 0, 0, 0);
        }
    }
#pragma unroll
    for (int ni = 0; ni < 4; ++ni) {
        int col = co0 + ni * 16 + r;
        if (col < 216) {
            float bb = omb[col];
#pragma unroll
            for (int mi = 0; mi < 2; ++mi)
#pragma unroll
                for (int reg = 0; reg < 4; ++reg)
                    som[mi * 16 + kq * 4 + reg][col] = acc[mi][ni][reg] + bb;
        }
    }
    __syncthreads();
    int tid = threadIdx.x;
#pragma unroll
    for (int i = 0; i < 18; ++i) {
        int j = i * 256 + tid;          // 32*144 = 4608
        int px = j / 144, col = j - px * 144;
        offo[(size_t)(p0 + px) * 144 + col] = som[px][col];
    }
    int px = tid >> 3, g = tid & 7;
    float mx = -1e30f;
#pragma unroll
    for (int p = 0; p < 9; ++p) mx = fmaxf(mx, som[px][144 + g * 9 + p]);
    float e[9], s = 0.f;
#pragma unroll
    for (int p = 0; p < 9; ++p) { e[p] = expf(som[px][144 + g * 9 + p] - mx); s += e[p]; }
    float inv = 1.f / s;
#pragma unroll
    for (int p = 0; p < 9; ++p) msko[(size_t)(p0 + px) * 72 + g * 9 + p] = e[p] * inv;
}

// ---------------- DCNv3 deformable sampling core (bf16 xproj) -> core_bf ----------------
__global__ __launch_bounds__(256) void k_core(const unsigned short* __restrict__ xp,
                                              const float* __restrict__ offo, const float* __restrict__ msko,
                                              unsigned short* __restrict__ core_bf) {
    int pix = blockIdx.x;
    int n = pix / HW_, hw = pix - n * HW_;
    int h = hw / W_,  w = hw - h * W_;
    int g  = threadIdx.x >> 5;
    int cc = threadIdx.x & 31;
    const float* op = offo + (size_t)pix * 144 + g * 18;
    const float* mp = msko + (size_t)pix * 72 + g * 9;
    const unsigned short* xg = xp + (size_t)n * HW_ * C_ + g * GC_ + cc;
    float acc = 0.f;
#pragma unroll
    for (int p = 0; p < 9; ++p) {
        float gx = (float)(w + (p / 3)) + op[p * 2];
        float gy = (float)(h + (p % 3)) + op[p * 2 + 1];
        float fx = floorf(gx), fy = floorf(gy);
        float wx = gx - fx,   wy = gy - fy;
        int ix = (int)fx - 1, iy = (int)fy - 1;
        float v00 = 0.f, v10 = 0.f, v01 = 0.f, v11 = 0.f;
        bool x0ok = (unsigned)ix < W_, x1ok = (unsigned)(ix + 1) < W_;
        bool y0ok = (unsigned)iy < H_, y1ok = (unsigned)(iy + 1) < H_;
        if (y0ok) {
            const unsigned short* rr = xg + (size_t)(iy * W_) * C_;
            if (x0ok) v00 = bf2f(rr[(size_t)ix * C_]);
            if (x1ok) v10 = bf2f(rr[(size_t)(ix + 1) * C_]);
        }
        if (y1ok) {
            const unsigned short* rr = xg + (size_t)((iy + 1) * W_) * C_;
            if (x0ok) v01 = bf2f(rr[(size_t)ix * C_]);
            if (x1ok) v11 = bf2f(rr[(size_t)(ix + 1) * C_]);
        }
        float sval = (v00 * (1.f - wx) + v10 * wx) * (1.f - wy)
                   + (v01 * (1.f - wx) + v11 * wx) * wy;
        acc = fmaf(mp[p], sval, acc);
    }
    core_bf[(size_t)pix * C_ + threadIdx.x] = f2bf(acc);
}

// ---------------- output proj MFMA + LN(1e-5) + gamma1 residual -> t, t_bf ----------------
__global__ __launch_bounds__(256) void k_outproj_mfma(const unsigned short* __restrict__ core_bf,
                                                      const unsigned short* __restrict__ outpwT,
                                                      const float* __restrict__ bo,
                                                      const float* __restrict__ g1, const float* __restrict__ lg,
                                                      const float* __restrict__ lb,
                                                      float* __restrict__ t, unsigned short* __restrict__ t_bf) {
    __shared__ float sd[32][260];
    int wave = threadIdx.x >> 6, lane = threadIdx.x & 63;
    int r = lane & 15, kq = lane >> 4;
    int p0 = blockIdx.x * 32, co0 = wave * 64;
    f32x4 acc[2][4] = {};
#pragma unroll 1
    for (int ks = 0; ks < 8; ++ks) {
        bf16x8 a0 = *(const bf16x8*)(core_bf + (size_t)(p0 + r) * C_ + ks * 32 + kq * 8);
        bf16x8 a1 = *(const bf16x8*)(core_bf + (size_t)(p0 + 16 + r) * C_ + ks * 32 + kq * 8);
        const unsigned short* bp = outpwT + (size_t)(co0 + r) * C_ + ks * 32 + kq * 8;
#pragma unroll
        for (int ni = 0; ni < 4; ++ni) {
            bf16x8 b = *(const bf16x8*)(bp + (size_t)ni * 16 * C_);
            acc[0][ni] = __builtin_amdgcn_mfma_f32_16x16x32_bf16(a0, b, acc[0][ni], 0, 0, 0);
            acc[1][ni] = __builtin_amdgcn_mfma_f32_16x16x32_bf16(a1, b, acc[1][ni], 0, 0, 0);
        }
    }
#pragma unroll
    for (int ni = 0; ni < 4; ++ni) {
        int col = co0 + ni * 16 + r;
        float bb = bo[col];
#pragma unroll
        for (int mi = 0; mi < 2; ++mi)
#pragma unroll
            for (int reg = 0; reg < 4; ++reg)
                sd[mi * 16 + kq * 4 + reg][col] = acc[mi][ni][reg] + bb;
    }
    __syncthreads();
    int px = threadIdx.x >> 3, sub = threadIdx.x & 7;
    float s1 = 0.f, s2 = 0.f;
#pragma unroll
    for (int i = 0; i < 8; ++i) {
        float4 vv = *(const float4*)&sd[px][sub * 32 + i * 4];
        s1 += vv.x + vv.y + vv.z + vv.w;
        s2 += vv.x * vv.x + vv.y * vv.y + vv.z * vv.z + vv.w * vv.w;
    }
#pragma unroll
    for (int off = 1; off < 8; off <<= 1) { s1 += __shfl_xor(s1, off, 64); s2 += __shfl_xor(s2, off, 64); }
    float mu  = s1 * (1.f / C_);
    float var = fmaxf(s2 * (1.f / C_) - mu * mu, 0.f);
    float rs  = rsqrtf(var + 1e-5f);
#pragma unroll
    for (int i = 0; i < 32; ++i) {
        int col = sub * 32 + i;
        size_t idx = (size_t)(p0 + px) * C_ + col;
        float tn = t[idx] + g1[col] * ((sd[px][col] - mu) * rs * lg[col] + lb[col]);
        t[idx] = tn;
        t_bf[idx] = f2bf(tn);
    }
}

// ---------------- fc1 GEMM (M=NHW,N=1024,K=256) + GELU -> h_bf ----------------
__global__ __launch_bounds__(256) void k_fc1_mfma(const unsigned short* __restrict__ t_bf,
                                                  const unsigned short* __restrict__ fc1wT,
                                                  const float* __restrict__ fc1b,
                                                  unsigned short* __restrict__ h_bf) {
    __shared__ __align__(16) unsigned char smem[34816];   // staging 32KB; out 128*136*2=34816B
    unsigned short* sm16 = (unsigned short*)smem;
    bf16x8* sA = (bf16x8*)smem;                 // 16 chunks * 64
    bf16x8* sB = (bf16x8*)(smem + 16384);       // 16 chunks * 64
    int tid = threadIdx.x;
    int wave = tid >> 6, lane = tid & 63;
    int r = lane & 15, kq = lane >> 4;
    int mt = blockIdx.x >> 3, nt = blockIdx.x & 7;
    int m0 = mt * 128, n0 = nt * 128;
    int wm = wave & 1, wn = wave >> 1;

    f32x4 acc[4][4] = {};
#pragma unroll 1
    for (int kt = 0; kt < 4; ++kt) {
        int k0 = kt * 64;
        if (kt) __syncthreads();
#pragma unroll
        for (int i = 0; i < 4; ++i) {          // A chunks q = wave*4+i
            int q = wave * 4 + i;
            int row = m0 + (q >> 1) * 16 + r;
            int cc  = (q & 1) * 4 + kq;
            GLOAD_LDS16(t_bf + (size_t)row * C_ + k0 + cc * 8, sm16 + q * 512);
        }
#pragma unroll
        for (int i = 0; i < 4; ++i) {          // B chunks q = wave*4+i
            int q = wave * 4 + i;
            int nrow = n0 + (q >> 1) * 16 + r;
            int cc   = (q & 1) * 4 + kq;
            GLOAD_LDS16(fc1wT + (size_t)nrow * C_ + k0 + cc * 8, sm16 + 8192 + q * 512);
        }
        __syncthreads();
#pragma unroll
        for (int ks = 0; ks < 2; ++ks) {
            bf16x8 af[4], bfr[4];
#pragma unroll
            for (int mi = 0; mi < 4; ++mi) af[mi]  = sA[((wm * 4 + mi) * 2 + ks) * 64 + lane];
#pragma unroll
            for (int ni = 0; ni < 4; ++ni) bfr[ni] = sB[((wn * 4 + ni) * 2 + ks) * 64 + lane];
#pragma unroll
            for (int mi = 0; mi < 4; ++mi)
#pragma unroll
                for (int ni = 0; ni < 4; ++ni)
                    acc[mi][ni] = __builtin_amdgcn_mfma_f32_16x16x32_bf16(af[mi], bfr[ni], acc[mi][ni], 0, 0, 0);
        }
    }
    __syncthreads();
#pragma unroll
    for (int ni = 0; ni < 4; ++ni) {
        int col = (wn * 4 + ni) * 16 + r;
        float bb = fc1b[n0 + col];
#pragma unroll
        for (int mi = 0; mi < 4; ++mi)
#pragma unroll
            for (int reg = 0; reg < 4; ++reg) {
                int row = (wm * 4 + mi) * 16 + kq * 4 + reg;
                sm16[row * 136 + col] = f2bf(gelu_exact(acc[mi][ni][reg] + bb));
            }
    }
    __syncthreads();
    int trow = tid >> 1, thalf = tid & 1;
    const unsigned short* src = sm16 + trow * 136 + thalf * 64;
    unsigned short* dst = h_bf + (size_t)(m0 + trow) * HID_ + n0 + thalf * 64;
#pragma unroll
    for (int j = 0; j < 8; ++j)
        *(bf16x8*)(dst + j * 8) = *(const bf16x8*)(src + j * 8);
}

// ---------------- fc2 GEMM + LN + gamma2 residual + BN2 + x-residual + ReLU -> out (NCHW) ----------------
__global__ __launch_bounds__(256) void k_fc2fin_mfma(const unsigned short* __restrict__ h_bf,
                                                     const unsigned short* __restrict__ fc2wT,
                                                     const float* __restrict__ fc2b,
                                                     const float* __restrict__ g2, const float* __restrict__ lg,
                                                     const float* __restrict__ lb, const float* __restrict__ t,
                                                     const float* __restrict__ x,
                                                     const float* __restrict__ bn2g, const float* __restrict__ bn2b,
                                                     const float* __restrict__ bn2m, const float* __restrict__ bn2v,
                                                     float* __restrict__ out) {
    __shared__ __align__(16) unsigned char smem[81920];   // 2 x (A 8KB + B 32KB); reused as ot[64][257] f32
    unsigned short* sm16 = (unsigned short*)smem;
    int tid = threadIdx.x;
    int wave = tid >> 6, lane = tid & 63;
    int r = lane & 15, kq = lane >> 4;
    int m0 = blockIdx.x * 64;

    f32x4 acc[16] = {};

    auto stage = [&](int kt, int buf) {
        int k0 = kt * 64;
        unsigned short* dstA = sm16 + buf * 20480;
        unsigned short* dstB = dstA + 4096;
#pragma unroll
        for (int i = 0; i < 2; ++i) {
            int q = wave * 2 + i;
            int row = m0 + wave * 16 + r;
            GLOAD_LDS16(h_bf + (size_t)row * HID_ + k0 + (i * 4 + kq) * 8, dstA + q * 512);
        }
#pragma unroll
        for (int i = 0; i < 8; ++i) {
            int q = wave * 8 + i;
            int nrow = (q >> 1) * 16 + r;
            int cc   = (q & 1) * 4 + kq;
            GLOAD_LDS16(fc2wT + (size_t)nrow * HID_ + k0 + cc * 8, dstB + q * 512);
        }
    };

    stage(0, 0);
    int cur = 0;
#pragma unroll 1
    for (int kt = 0; kt < 16; ++kt) {
        if (kt < 15) {
            stage(kt + 1, cur ^ 1);
            asm volatile("s_waitcnt vmcnt(10)" ::: "memory");
        } else {
            asm volatile("s_waitcnt vmcnt(0)" ::: "memory");
        }
        __builtin_amdgcn_s_barrier();
        bf16x8* sA = (bf16x8*)(sm16 + cur * 20480);
        bf16x8* sB = sA + 512;
#pragma unroll
        for (int ks = 0; ks < 2; ++ks) {
            bf16x8 a = sA[(wave * 2 + ks) * 64 + lane];
#pragma unroll
            for (int ni = 0; ni < 16; ++ni) {
                bf16x8 b = sB[(ni * 2 + ks) * 64 + lane];
                acc[ni] = __builtin_amdgcn_mfma_f32_16x16x32_bf16(a, b, acc[ni], 0, 0, 0);
            }
        }
        __builtin_amdgcn_s_barrier();
        cur ^= 1;
    }

    // epilogue 1: bias, per-row LN (in-wave), gamma2 residual -> ot[64][257] in LDS
    float* ot = (float*)smem;
    float bb[16], g2v[16], lgv[16], lbv[16];
#pragma unroll
    for (int ni = 0; ni < 16; ++ni) {
        int col = ni * 16 + r;
        bb[ni] = fc2b[col]; g2v[ni] = g2[col]; lgv[ni] = lg[col]; lbv[ni] = lb[col];
    }
#pragma unroll
    for (int ni = 0; ni < 16; ++ni)
#pragma unroll
        for (int reg = 0; reg < 4; ++reg) acc[ni][reg] += bb[ni];
#pragma unroll
    for (int reg = 0; reg < 4; ++reg) {
        float s1 = 0.f, s2 = 0.f;
#pragma unroll
        for (int ni = 0; ni < 16; ++ni) { float vv = acc[ni][reg]; s1 += vv; s2 += vv * vv; }
#pragma unroll
        for (int off = 1; off < 16; off <<= 1) { s1 += __shfl_xor(s1, off, 64); s2 += __shfl_xor(s2, off, 64); }
        float mu  = s1 * (1.f / C_);
        float var = fmaxf(s2 * (1.f / C_) - mu * mu, 0.f);
        float rs  = rsqrtf(var + 1e-5f);
        int row_local = wave * 16 + kq * 4 + reg;
        const float* tr = t + (size_t)(m0 + row_local) * C_;
#pragma unroll
        for (int ni = 0; ni < 16; ++ni) {
            int col = ni * 16 + r;
            ot[row_local * 257 + col] = tr[col] + g2v[ni] * ((acc[ni][reg] - mu) * rs * lgv[ni] + lbv[ni]);
        }
    }
    __syncthreads();

    // epilogue 2: BN2 + x residual + ReLU, NCHW coalesced writes (lane = hw, per-channel 256B runs)
    int n  = m0 / HW_;
    int hw0 = m0 - n * HW_;
#pragma unroll 1
    for (int i = 0; i < 64; ++i) {
        int c = wave * 64 + i;                 // wave-uniform channel
        float sc = bn2g[c] * rsqrtf(bn2v[c] + 1e-5f);
        float sh = bn2b[c] - bn2m[c] * sc;
        size_t gidx = ((size_t)(n * C_ + c)) * HW_ + hw0 + lane;
        float val = ot[lane * 257 + c] * sc + sh + x[gidx];
        out[gidx] = fmaxf(val, 0.f);
    }
}

extern "C" void kernel_launch(void* const* d_in, const int* in_sizes, int n_in,
                              void* d_out, int out_size, void* d_ws, size_t ws_size,
                              hipStream_t stream) {
    const float* x      = (const float*)d_in[0];
    const float* conv1w = (const float*)d_in[1];
    const float* bn1g   = (const float*)d_in[2];
    const float* bn1b   = (const float*)d_in[3];
    const float* bn1m   = (const float*)d_in[4];
    const float* bn1v   = (const float*)d_in[5];
    const float* ln1g   = (const float*)d_in[6];
    const float* ln1b   = (const float*)d_in[7];
    const float* dww    = (const float*)d_in[8];
    const float* dwb    = (const float*)d_in[9];
    const float* dwlng  = (const float*)d_in[10];
    const float* dwlnb  = (const float*)d_in[11];
    const float* offw   = (const float*)d_in[12];
    const float* offb   = (const float*)d_in[13];
    const float* mskw   = (const float*)d_in[14];
    const float* mskb   = (const float*)d_in[15];
    const float* inpw   = (const float*)d_in[16];
    const float* inpb   = (const float*)d_in[17];
    const float* outpw  = (const float*)d_in[18];
    const float* outpb  = (const float*)d_in[19];
    const float* gamma1 = (const float*)d_in[20];
    const float* ln2g   = (const float*)d_in[21];
    const float* ln2b   = (const float*)d_in[22];
    const float* fc1w   = (const float*)d_in[23];
    const float* fc1b   = (const float*)d_in[24];
    const float* fc2w   = (const float*)d_in[25];
    const float* fc2b   = (const float*)d_in[26];
    const float* gamma2 = (const float*)d_in[27];
    const float* bn2g   = (const float*)d_in[28];
    const float* bn2b   = (const float*)d_in[29];
    const float* bn2m   = (const float*)d_in[30];
    const float* bn2v   = (const float*)d_in[31];
    float* out = (float*)d_out;

    // ---- workspace layout ----
    // Front region (51.4MB): h_bf for MLP, aliasing {xproj_bf, offo, msko, x1_bf} (all dead by fc1).
    unsigned short* h_bf     = (unsigned short*)d_ws;                        // [NHW][1024] bf16
    unsigned short* xproj_bf = (unsigned short*)d_ws;                        // [NHW][256] bf16
    float* offo  = (float*)(xproj_bf + (size_t)NHW_ * C_);                   // [NHW][144] f32
    float* msko  = offo + (size_t)NHW_ * 144;                                // [NHW][72]  f32
    unsigned short* x1_bf = (unsigned short*)(msko + (size_t)NHW_ * 72);     // [NHW][256] bf16
    // (front usage 47.3MB <= h_bf's 51.4MB)
    unsigned short* scr   = h_bf + (size_t)NHW_ * HID_;   // xpad / core_bf alias (13.78MB)
    float* t     = (float*)(scr + (size_t)N_ * XP_H * XP_W * C_);            // [NHW][256] f32
    float* omb   = t + (size_t)NHW_ * C_;                 // [256] f32
    unsigned short* t_bf  = (unsigned short*)(omb + 256); // [NHW][256]
    unsigned short* wTT   = t_bf  + (size_t)NHW_ * C_;    // [9][256][256]
    unsigned short* inpwT = wTT   + (size_t)9 * C_ * C_;  // [256][256]
    unsigned short* outpwT= inpwT + (size_t)C_ * C_;
    unsigned short* fc1wT = outpwT+ (size_t)C_ * C_;      // [1024][256]
    unsigned short* fc2wT = fc1wT + (size_t)HID_ * C_;    // [256][1024]
    unsigned short* omT   = fc2wT + (size_t)C_ * HID_;    // [256][256]
    unsigned short* xpad    = scr;
    unsigned short* core_bf = scr;

    hipMemsetAsync(xpad, 0, (size_t)N_ * XP_H * XP_W * C_ * sizeof(unsigned short), stream);
    k_prep_xpad<<<N_ * H_, 256, 0, stream>>>(x, xpad);
    k_prep_wTT <<<2304,    256, 0, stream>>>(conv1w, wTT);
    k_prep_sqT <<<256,     256, 0, stream>>>(inpw, inpwT);
    k_prep_sqT <<<256,     256, 0, stream>>>(outpw, outpwT);
    k_prep_fc1T<<<1024,    256, 0, stream>>>(fc1w, fc1wT);
    k_prep_fc2T<<<256,     256, 0, stream>>>(fc2w, fc2wT);
    k_prep_om  <<<256,     256, 0, stream>>>(offw, offb, mskw, mskb, omT, omb);

    k_conv1_mfma  <<<(NHW_ / 128) * 2, 256, 0, stream>>>(xpad, wTT, bn1g, bn1b, bn1m, bn1v, t, t_bf);
    k_inproj_mfma <<<NHW_ / 64, 256, 0, stream>>>(t_bf, inpwT, inpb, xproj_bf);
    k_dw          <<<NHW_ / 4,  256, 0, stream>>>(t_bf, dww, dwb, dwlng, dwlnb, x1_bf);
    k_offmask_mfma<<<NHW_ / 32, 256, 0, stream>>>(x1_bf, omT, omb, offo, msko);
    k_core        <<<NHW_,      256, 0, stream>>>(xproj_bf, offo, msko, core_bf);
    k_outproj_mfma<<<NHW_ / 32, 256, 0, stream>>>(core_bf, outpwT, outpb, gamma1, ln1g, ln1b, t, t_bf);
    k_fc1_mfma    <<<(NHW_ / 128) * 8, 256, 0, stream>>>(t_bf, fc1wT, fc1b, h_bf);
    k_fc2fin_mfma <<<NHW_ / 64, 256, 0, stream>>>(h_bf, fc2wT, fc2b, gamma2, ln2g, ln2b, t,
                                                  x, bn2g, bn2b, bn2m, bn2v, out);
}

// Round 11
// 537.823 us; speedup vs baseline: 1.3162x; 1.3162x over previous
//
#include <hip/hip_runtime.h>
#include <cmath>

#define N_   8
#define H_   56
#define W_   56
#define C_   256
#define HW_  3136
#define NHW_ 25088
#define G_   8
#define GC_  32
#define P_   9
#define HID_ 1024
#define XP_H 58
#define XP_W 58

typedef __attribute__((ext_vector_type(8))) short bf16x8;
typedef __attribute__((ext_vector_type(4))) float f32x4;

#define GLOAD_LDS16(g, l) __builtin_amdgcn_global_load_lds( \
    (const __attribute__((address_space(1))) void*)(g), \
    (__attribute__((address_space(3))) void*)(l), 16, 0, 0)

__device__ __forceinline__ unsigned short f2bf(float f) {
    unsigned u = __float_as_uint(f);
    u += 0x7FFF + ((u >> 16) & 1);   // round-to-nearest-even
    return (unsigned short)(u >> 16);
}

__device__ __forceinline__ float bf2f(unsigned short u) {
    return __uint_as_float((unsigned)u << 16);
}

__device__ __forceinline__ float gelu_exact(float v) {
    return 0.5f * v * (1.f + erff(v * 0.70710678118654752f));
}

// ---------------- block-wide sum of (a,b) over 256 threads ----------------
__device__ __forceinline__ float2 block_sum2(float a, float b, float* sm) {
    int lane = threadIdx.x & 63;
    int wid  = threadIdx.x >> 6;
#pragma unroll
    for (int off = 32; off > 0; off >>= 1) {
        a += __shfl_down(a, off, 64);
        b += __shfl_down(b, off, 64);
    }
    if (lane == 0) { sm[wid] = a; sm[wid + 4] = b; }
    __syncthreads();
    float ra = sm[0] + sm[1] + sm[2] + sm[3];
    float rb = sm[4] + sm[5] + sm[6] + sm[7];
    __syncthreads();
    return make_float2(ra, rb);
}

// ---------------- x (NCHW fp32) -> xpad (N,58,58,256 bf16), border pre-zeroed ----------------
__global__ __launch_bounds__(256) void k_prep_xpad(const float* __restrict__ x, unsigned short* __restrict__ xpad) {
    int nh = blockIdx.x;                   // N_*H_ = 448
    int n = nh / H_, h = nh - n * H_;
    int c = threadIdx.x;
    const float* xr = x + ((size_t)(n * C_ + c)) * HW_ + h * W_;
    unsigned short* orow = xpad + ((size_t)((n * XP_H + h + 1) * XP_W + 1)) * C_ + c;
    for (int w = 0; w < W_; ++w) orow[(size_t)w * C_] = f2bf(xr[w]);
}

// ---------------- conv1 weights [co][ci][3][3] -> wTT [kk][co][ci] bf16 ----------------
__global__ __launch_bounds__(256) void k_prep_wTT(const float* __restrict__ w, unsigned short* __restrict__ wTT) {
    int i  = blockIdx.x * 256 + threadIdx.x;   // 9*256*256
    int ci = i & 255;
    int r  = i >> 8;
    int co = r & 255;
    int kk = r >> 8;
    wTT[i] = f2bf(w[(co * 256 + ci) * 9 + kk]);
}

// ---------------- square 256x256 weight -> W^T bf16 [n][k] ----------------
__global__ __launch_bounds__(256) void k_prep_sqT(const float* __restrict__ src, unsigned short* __restrict__ dst) {
    int n = blockIdx.x, k = threadIdx.x;
    dst[n * C_ + k] = f2bf(src[k * C_ + n]);
}

// ---------------- fc1 [256][1024] -> [1024][256] bf16 ----------------
__global__ __launch_bounds__(256) void k_prep_fc1T(const float* __restrict__ src, unsigned short* __restrict__ dst) {
    int n = blockIdx.x, k = threadIdx.x;
    dst[(size_t)n * C_ + k] = f2bf(src[(size_t)k * HID_ + n]);
}

// ---------------- fc2 [1024][256] -> [256][1024] bf16 ----------------
__global__ __launch_bounds__(256) void k_prep_fc2T(const float* __restrict__ src, unsigned short* __restrict__ dst) {
    int n = blockIdx.x, k0 = threadIdx.x;
#pragma unroll
    for (int q = 0; q < 4; ++q) {
        int k = q * 256 + k0;
        dst[(size_t)n * HID_ + k] = f2bf(src[(size_t)k * C_ + n]);
    }
}

// ---------------- offw[256][144] + mskw[256][72] -> omT [256][256] bf16 (+ omb) ----------------
__global__ __launch_bounds__(256) void k_prep_om(const float* __restrict__ offw, const float* __restrict__ offb,
                                                 const float* __restrict__ mskw, const float* __restrict__ mskb,
                                                 unsigned short* __restrict__ omT, float* __restrict__ omb) {
    int n = blockIdx.x, k = threadIdx.x;
    float v = 0.f;
    if (n < 144)      v = offw[k * 144 + n];
    else if (n < 216) v = mskw[k * 72 + (n - 144)];
    omT[n * C_ + k] = f2bf(v);
    if (k == 0) omb[n] = (n < 144) ? offb[n] : (n < 216 ? mskb[n - 144] : 0.f);
}

// ---------------- conv1 implicit GEMM: 128x128 tile, BK=32 (m97 proportions), dbuf + swizzle ----------------
__global__ __launch_bounds__(256) void k_conv1_mfma(const unsigned short* __restrict__ xpad,
                                                    const unsigned short* __restrict__ wTT,
                                                    const float* __restrict__ g, const float* __restrict__ b,
                                                    const float* __restrict__ m, const float* __restrict__ v,
                                                    float* __restrict__ t, unsigned short* __restrict__ t_bf) {
    __shared__ __align__(16) unsigned char smem[32768];   // 2 x (A 8KB + B 8KB)
    unsigned short* sm16 = (unsigned short*)smem;
    int tid = threadIdx.x;
    int wave = tid >> 6, lane = tid & 63;
    int r = lane & 15, kq = lane >> 4;
    int bid = blockIdx.x;                    // 392 = 8 * 49
    int swz = (bid & 7) * 49 + (bid >> 3);   // bijective XCD-band swizzle
    int mt = swz >> 1, nt = swz & 1;
    int m0 = mt * 128, n0 = nt * 128;
    int wm = wave & 1, wn = wave >> 1;

    size_t abase[2];
#pragma unroll
    for (int i = 0; i < 2; ++i) {
        int pix = m0 + (wave * 2 + i) * 16 + r;
        int n = pix / HW_, hw = pix - n * HW_;
        int h = hw / W_, w = hw - h * W_;
        abase[i] = ((size_t)((n * XP_H + h) * XP_W + w)) * C_ + kq * 8;
    }

    f32x4 acc[4][4] = {};

    auto stage = [&](int kt, int buf) {
        int tap = kt >> 3, ktk = kt & 7;
        int kh = tap / 3, kw = tap - kh * 3;
        int k0 = ktk * 32;
        unsigned short* dstA = sm16 + buf * 8192;
        unsigned short* dstB = dstA + 4096;
        size_t aoff = (size_t)(kh * XP_W + kw) * C_ + k0;
#pragma unroll
        for (int i = 0; i < 2; ++i) {
            int q = wave * 2 + i;
            GLOAD_LDS16(xpad + abase[i] + aoff, dstA + q * 512);
        }
#pragma unroll
        for (int i = 0; i < 2; ++i) {
            int q = wave * 2 + i;
            int nrow = n0 + q * 16 + r;
            GLOAD_LDS16(wTT + ((size_t)(tap * C_) + nrow) * C_ + k0 + kq * 8, dstB + q * 512);
        }
    };

    stage(0, 0);
    int cur = 0;
#pragma unroll 1
    for (int kt = 0; kt < 72; ++kt) {
        if (kt < 71) {
            stage(kt + 1, cur ^ 1);
            asm volatile("s_waitcnt vmcnt(4)" ::: "memory");
        } else {
            asm volatile("s_waitcnt vmcnt(0)" ::: "memory");
        }
        __builtin_amdgcn_s_barrier();
        bf16x8* sA = (bf16x8*)(sm16 + cur * 8192);
        bf16x8* sB = sA + 512;
        bf16x8 af[4], bfr[4];
#pragma unroll
        for (int mi = 0; mi < 4; ++mi) af[mi]  = sA[(wm * 4 + mi) * 64 + lane];
#pragma unroll
        for (int ni = 0; ni < 4; ++ni) bfr[ni] = sB[(wn * 4 + ni) * 64 + lane];
#pragma unroll
        for (int mi = 0; mi < 4; ++mi)
#pragma unroll
            for (int ni = 0; ni < 4; ++ni)
                acc[mi][ni] = __builtin_amdgcn_mfma_f32_16x16x32_bf16(af[mi], bfr[ni], acc[mi][ni], 0, 0, 0);
        __builtin_amdgcn_s_barrier();
        cur ^= 1;
    }

#pragma unroll
    for (int ni = 0; ni < 4; ++ni) {
        int co = n0 + (wn * 4 + ni) * 16 + r;
        float sc = g[co] * rsqrtf(v[co] + 1e-5f);
        float sh = b[co] - m[co] * sc;
#pragma unroll
        for (int mi = 0; mi < 4; ++mi) {
#pragma unroll
            for (int reg = 0; reg < 4; ++reg) {
                int po = m0 + (wm * 4 + mi) * 16 + kq * 4 + reg;
                float val = fmaxf(acc[mi][ni][reg] * sc + sh, 0.f);
                size_t idx = (size_t)po * C_ + co;
                t[idx] = val;
                t_bf[idx] = f2bf(val);
            }
        }
    }
}

// ---------------- input proj: 64x256 staged-dbuf GEMM (K=256) -> xproj_bf (bf16) ----------------
__global__ __launch_bounds__(256) void k_inproj_mfma(const unsigned short* __restrict__ t_bf,
                                                     const unsigned short* __restrict__ inpwT,
                                                     const float* __restrict__ bias,
                                                     unsigned short* __restrict__ xproj_bf) {
    __shared__ __align__(16) unsigned char smem[81920];   // 2 x (A 8KB + B 32KB)
    unsigned short* sm16 = (unsigned short*)smem;
    int tid = threadIdx.x;
    int wave = tid >> 6, lane = tid & 63;
    int r = lane & 15, kq = lane >> 4;
    int m0 = blockIdx.x * 64;

    f32x4 acc[16] = {};

    auto stage = [&](int kt, int buf) {
        int k0 = kt * 64;
        unsigned short* dstA = sm16 + buf * 20480;
        unsigned short* dstB = dstA + 4096;
#pragma unroll
        for (int i = 0; i < 2; ++i) {
            int q = wave * 2 + i;
            int row = m0 + wave * 16 + r;
            GLOAD_LDS16(t_bf + (size_t)row * C_ + k0 + (i * 4 + kq) * 8, dstA + q * 512);
        }
#pragma unroll
        for (int i = 0; i < 8; ++i) {
            int q = wave * 8 + i;
            int nrow = (q >> 1) * 16 + r;
            int cc   = (q & 1) * 4 + kq;
            GLOAD_LDS16(inpwT + (size_t)nrow * C_ + k0 + cc * 8, dstB + q * 512);
        }
    };

    stage(0, 0);
    int cur = 0;
#pragma unroll 1
    for (int kt = 0; kt < 4; ++kt) {
        if (kt < 3) {
            stage(kt + 1, cur ^ 1);
            asm volatile("s_waitcnt vmcnt(10)" ::: "memory");
        } else {
            asm volatile("s_waitcnt vmcnt(0)" ::: "memory");
        }
        __builtin_amdgcn_s_barrier();
        bf16x8* sA = (bf16x8*)(sm16 + cur * 20480);
        bf16x8* sB = sA + 512;
#pragma unroll
        for (int ks = 0; ks < 2; ++ks) {
            bf16x8 a = sA[(wave * 2 + ks) * 64 + lane];
#pragma unroll
            for (int ni = 0; ni < 16; ++ni) {
                bf16x8 b = sB[(ni * 2 + ks) * 64 + lane];
                acc[ni] = __builtin_amdgcn_mfma_f32_16x16x32_bf16(a, b, acc[ni], 0, 0, 0);
            }
        }
        __builtin_amdgcn_s_barrier();
        cur ^= 1;
    }

#pragma unroll
    for (int ni = 0; ni < 16; ++ni) {
        int col = ni * 16 + r;
        float bb = bias[col];
#pragma unroll
        for (int reg = 0; reg < 4; ++reg) {
            int row = m0 + wave * 16 + kq * 4 + reg;
            xproj_bf[(size_t)row * C_ + col] = f2bf(acc[ni][reg] + bb);
        }
    }
}

// ---------------- depthwise 3x3 + LN(1e-6) + exact GELU -> x1_bf (4 pixels/block, bf16 input) ----------------
__global__ __launch_bounds__(256) void k_dw(const unsigned short* __restrict__ t_bf, const float* __restrict__ dww,
                                            const float* __restrict__ dwb, const float* __restrict__ lg,
                                            const float* __restrict__ lb, unsigned short* __restrict__ x1_bf) {
    __shared__ float sm[8];
    int p0 = blockIdx.x * 4;               // NHW_/4 blocks; groups never cross rows (W_%4==0)
    int n = p0 / HW_, hw = p0 - n * HW_;
    int h = hw / W_, w0 = hw - h * W_;
    int c = threadIdx.x;

    float vals[3][6];
#pragma unroll
    for (int dy = 0; dy < 3; ++dy) {
        int y = h + dy - 1;
        bool rowok = (unsigned)y < H_;
#pragma unroll
        for (int dx = 0; dx < 6; ++dx) {
            int xx = w0 + dx - 1;
            bool ok = rowok && ((unsigned)xx < W_);
            vals[dy][dx] = ok ? bf2f(t_bf[((size_t)(n * HW_ + y * W_ + xx)) * C_ + c]) : 0.f;
        }
    }
    float wv[9];
#pragma unroll
    for (int k = 0; k < 9; ++k) wv[k] = dww[k * C_ + c];
    float bias = dwb[c], lgc = lg[c], lbc = lb[c];

#pragma unroll 1
    for (int px = 0; px < 4; ++px) {
        float acc = bias;
#pragma unroll
        for (int kh = 0; kh < 3; ++kh)
#pragma unroll
            for (int kw = 0; kw < 3; ++kw)
                acc = fmaf(vals[kh][px + kw], wv[kh * 3 + kw], acc);
        float2 rr = block_sum2(acc, acc * acc, sm);
        float mu  = rr.x * (1.f / C_);
        float var = fmaxf(rr.y * (1.f / C_) - mu * mu, 0.f);
        float rs  = rsqrtf(var + 1e-6f);
        float val = (acc - mu) * rs * lgc + lbc;
        x1_bf[(size_t)(p0 + px) * C_ + c] = f2bf(gelu_exact(val));
    }
}

// ---------------- offset+mask via MFMA (N=256: 144 off | 72 msk | 40 pad) + softmax ----------------
__global__ __launch_bounds__(256) void k_offmask_mfma(const unsigned short* __restrict__ x1_bf,
                                                      const unsigned short* __restrict__ omT,
                                                      const float* __restrict__ omb,
                                                      float* __restrict__ offo, float* __restrict__ msko) {
    __shared__ float som[32][225];
    int wave = threadIdx.x >> 6, lane = threadIdx.x & 63;
    int r = lane & 15, kq = lane >> 4;
    int p0 = blockIdx.x * 32, co0 = wave * 64;
    f32x4 acc[2][4] = {};
#pragma unroll 1
    for (int ks = 0; ks < 8; ++ks) {
        bf16x8 a0 = *(const bf16x8*)(x1_bf + (size_t)(p0 + r) * C_ + ks * 32 + kq * 8);
        bf16x8 a1 = *(const bf16x8*)(x1_bf + (size_t)(p0 + 16 + r) * C_ + ks * 32 + kq * 8);
        const unsigned short* bp = omT + (size_t)(co0 + r) * C_ + ks * 32 + kq * 8;
#pragma unroll
        for (int ni = 0; ni < 4; ++ni) {
            bf16x8 b = *(const bf16x8*)(bp + (size_t)ni * 16 * C_);
            acc[0][ni] = __builtin_amdgcn_mfma_f32_16x16x32_bf16(a0, b, acc[0][ni], 0, 0, 0);
            acc[1][ni] = __builtin_amdgcn_mfma_f32_16x16x32_bf16(a1, b, acc[1][ni], 0, 0, 0);
        }
    }
#pragma unroll
    for (int ni = 0; ni < 4; ++ni) {
        int col = co0 + ni * 16 + r;
        if (col < 216) {
            float bb = omb[col];
#pragma unroll
            for (int mi = 0; mi < 2; ++mi)
#pragma unroll
                for (int reg = 0; reg < 4; ++reg)
                    som[mi * 16 + kq * 4 + reg][col] = acc[mi][ni][reg] + bb;
        }
    }
    __syncthreads();
    int tid = threadIdx.x;
#pragma unroll
    for (int i = 0; i < 18; ++i) {
        int j = i * 256 + tid;          // 32*144 = 4608
        int px = j / 144, col = j - px * 144;
        offo[(size_t)(p0 + px) * 144 + col] = som[px][col];
    }
    int px = tid >> 3, g = tid & 7;
    float mx = -1e30f;
#pragma unroll
    for (int p = 0; p < 9; ++p) mx = fmaxf(mx, som[px][144 + g * 9 + p]);
    float e[9], s = 0.f;
#pragma unroll
    for (int p = 0; p < 9; ++p) { e[p] = expf(som[px][144 + g * 9 + p] - mx); s += e[p]; }
    float inv = 1.f / s;
#pragma unroll
    for (int p = 0; p < 9; ++p) msko[(size_t)(p0 + px) * 72 + g * 9 + p] = e[p] * inv;
}

// ---------------- DCNv3 core, channel-vectorized: thread = (pix8, g, cc-octet), 16B gathers ----------------
__global__ __launch_bounds__(256) void k_core(const unsigned short* __restrict__ xp,
                                              const float* __restrict__ offo, const float* __restrict__ msko,
                                              unsigned short* __restrict__ core_bf) {
    int tid  = threadIdx.x;
    int pix8 = tid >> 5;            // 8 pixels per block
    int g    = (tid >> 2) & 7;      // 8 groups
    int cc8  = tid & 3;             // 4 octets of 8 channels
    int pix  = blockIdx.x * 8 + pix8;
    int n = pix / HW_, hw = pix - n * HW_;
    int h = hw / W_,  w = hw - h * W_;
    const float* op = offo + (size_t)pix * 144 + g * 18;
    const float* mp = msko + (size_t)pix * 72 + g * 9;
    const unsigned short* xg = xp + (size_t)n * HW_ * C_ + g * GC_ + cc8 * 8;

    float acc[8] = {};
    const bf16x8 vz = {};
#pragma unroll
    for (int p = 0; p < 9; ++p) {
        float gx = (float)(w + (p / 3)) + op[p * 2];
        float gy = (float)(h + (p % 3)) + op[p * 2 + 1];
        float fx = floorf(gx), fy = floorf(gy);
        float wx = gx - fx,   wy = gy - fy;
        int ix = (int)fx - 1, iy = (int)fy - 1;
        bool x0ok = (unsigned)ix < W_, x1ok = (unsigned)(ix + 1) < W_;
        bool y0ok = (unsigned)iy < H_, y1ok = (unsigned)(iy + 1) < H_;
        bf16x8 v00 = vz, v10 = vz, v01 = vz, v11 = vz;
        if (y0ok) {
            const unsigned short* rr = xg + (size_t)(iy * W_) * C_;
            if (x0ok) v00 = *(const bf16x8*)(rr + (size_t)ix * C_);
            if (x1ok) v10 = *(const bf16x8*)(rr + (size_t)(ix + 1) * C_);
        }
        if (y1ok) {
            const unsigned short* rr = xg + (size_t)((iy + 1) * W_) * C_;
            if (x0ok) v01 = *(const bf16x8*)(rr + (size_t)ix * C_);
            if (x1ok) v11 = *(const bf16x8*)(rr + (size_t)(ix + 1) * C_);
        }
        float mk  = mp[p];
        float w00 = (1.f - wx) * (1.f - wy) * mk;
        float w10 = wx * (1.f - wy) * mk;
        float w01 = (1.f - wx) * wy * mk;
        float w11 = wx * wy * mk;
#pragma unroll
        for (int j = 0; j < 8; ++j) {
            float s = w00 * bf2f((unsigned short)v00[j]) + w10 * bf2f((unsigned short)v10[j])
                    + w01 * bf2f((unsigned short)v01[j]) + w11 * bf2f((unsigned short)v11[j]);
            acc[j] += s;
        }
    }
    unsigned short outv[8];
#pragma unroll
    for (int j = 0; j < 8; ++j) outv[j] = f2bf(acc[j]);
    *(bf16x8*)(core_bf + (size_t)pix * C_ + g * GC_ + cc8 * 8) = *(const bf16x8*)outv;
}

// ---------------- output proj MFMA + LN(1e-5) + gamma1 residual -> t, t_bf ----------------
__global__ __launch_bounds__(256) void k_outproj_mfma(const unsigned short* __restrict__ core_bf,
                                                      const unsigned short* __restrict__ outpwT,
                                                      const float* __restrict__ bo,
                                                      const float* __restrict__ g1, const float* __restrict__ lg,
                                                      const float* __restrict__ lb,
                                                      float* __restrict__ t, unsigned short* __restrict__ t_bf) {
    __shared__ float sd[32][260];
    int wave = threadIdx.x >> 6, lane = threadIdx.x & 63;
    int r = lane & 15, kq = lane >> 4;
    int p0 = blockIdx.x * 32, co0 = wave * 64;
    f32x4 acc[2][4] = {};
#pragma unroll 1
    for (int ks = 0; ks < 8; ++ks) {
        bf16x8 a0 = *(const bf16x8*)(core_bf + (size_t)(p0 + r) * C_ + ks * 32 + kq * 8);
        bf16x8 a1 = *(const bf16x8*)(core_bf + (size_t)(p0 + 16 + r) * C_ + ks * 32 + kq * 8);
        const unsigned short* bp = outpwT + (size_t)(co0 + r) * C_ + ks * 32 + kq * 8;
#pragma unroll
        for (int ni = 0; ni < 4; ++ni) {
            bf16x8 b = *(const bf16x8*)(bp + (size_t)ni * 16 * C_);
            acc[0][ni] = __builtin_amdgcn_mfma_f32_16x16x32_bf16(a0, b, acc[0][ni], 0, 0, 0);
            acc[1][ni] = __builtin_amdgcn_mfma_f32_16x16x32_bf16(a1, b, acc[1][ni], 0, 0, 0);
        }
    }
#pragma unroll
    for (int ni = 0; ni < 4; ++ni) {
        int col = co0 + ni * 16 + r;
        float bb = bo[col];
#pragma unroll
        for (int mi = 0; mi < 2; ++mi)
#pragma unroll
            for (int reg = 0; reg < 4; ++reg)
                sd[mi * 16 + kq * 4 + reg][col] = acc[mi][ni][reg] + bb;
    }
    __syncthreads();
    int px = threadIdx.x >> 3, sub = threadIdx.x & 7;
    float s1 = 0.f, s2 = 0.f;
#pragma unroll
    for (int i = 0; i < 8; ++i) {
        float4 vv = *(const float4*)&sd[px][sub * 32 + i * 4];
        s1 += vv.x + vv.y + vv.z + vv.w;
        s2 += vv.x * vv.x + vv.y * vv.y + vv.z * vv.z + vv.w * vv.w;
    }
#pragma unroll
    for (int off = 1; off < 8; off <<= 1) { s1 += __shfl_xor(s1, off, 64); s2 += __shfl_xor(s2, off, 64); }
    float mu  = s1 * (1.f / C_);
    float var = fmaxf(s2 * (1.f / C_) - mu * mu, 0.f);
    float rs  = rsqrtf(var + 1e-5f);
#pragma unroll
    for (int i = 0; i < 32; ++i) {
        int col = sub * 32 + i;
        size_t idx = (size_t)(p0 + px) * C_ + col;
        float tn = t[idx] + g1[col] * ((sd[px][col] - mu) * rs * lg[col] + lb[col]);
        t[idx] = tn;
        t_bf[idx] = f2bf(tn);
    }
}

// ---------------- fc1 GEMM (M=NHW,N=1024,K=256) + GELU -> h_bf ----------------
__global__ __launch_bounds__(256) void k_fc1_mfma(const unsigned short* __restrict__ t_bf,
                                                  const unsigned short* __restrict__ fc1wT,
                                                  const float* __restrict__ fc1b,
                                                  unsigned short* __restrict__ h_bf) {
    __shared__ __align__(16) unsigned char smem[34816];   // staging 32KB; out 128*136*2=34816B
    unsigned short* sm16 = (unsigned short*)smem;
    bf16x8* sA = (bf16x8*)smem;                 // 16 chunks * 64
    bf16x8* sB = (bf16x8*)(smem + 16384);       // 16 chunks * 64
    int tid = threadIdx.x;
    int wave = tid >> 6, lane = tid & 63;
    int r = lane & 15, kq = lane >> 4;
    int mt = blockIdx.x >> 3, nt = blockIdx.x & 7;
    int m0 = mt * 128, n0 = nt * 128;
    int wm = wave & 1, wn = wave >> 1;

    f32x4 acc[4][4] = {};
#pragma unroll 1
    for (int kt = 0; kt < 4; ++kt) {
        int k0 = kt * 64;
        if (kt) __syncthreads();
#pragma unroll
        for (int i = 0; i < 4; ++i) {          // A chunks q = wave*4+i
            int q = wave * 4 + i;
            int row = m0 + (q >> 1) * 16 + r;
            int cc  = (q & 1) * 4 + kq;
            GLOAD_LDS16(t_bf + (size_t)row * C_ + k0 + cc * 8, sm16 + q * 512);
        }
#pragma unroll
        for (int i = 0; i < 4; ++i) {          // B chunks q = wave*4+i
            int q = wave * 4 + i;
            int nrow = n0 + (q >> 1) * 16 + r;
            int cc   = (q & 1) * 4 + kq;
            GLOAD_LDS16(fc1wT + (size_t)nrow * C_ + k0 + cc * 8, sm16 + 8192 + q * 512);
        }
        __syncthreads();
#pragma unroll
        for (int ks = 0; ks < 2; ++ks) {
            bf16x8 af[4], bfr[4];
#pragma unroll
            for (int mi = 0; mi < 4; ++mi) af[mi]  = sA[((wm * 4 + mi) * 2 + ks) * 64 + lane];
#pragma unroll
            for (int ni = 0; ni < 4; ++ni) bfr[ni] = sB[((wn * 4 + ni) * 2 + ks) * 64 + lane];
#pragma unroll
            for (int mi = 0; mi < 4; ++mi)
#pragma unroll
                for (int ni = 0; ni < 4; ++ni)
                    acc[mi][ni] = __builtin_amdgcn_mfma_f32_16x16x32_bf16(af[mi], bfr[ni], acc[mi][ni], 0, 0, 0);
        }
    }
    __syncthreads();
#pragma unroll
    for (int ni = 0; ni < 4; ++ni) {
        int col = (wn * 4 + ni) * 16 + r;
        float bb = fc1b[n0 + col];
#pragma unroll
        for (int mi = 0; mi < 4; ++mi)
#pragma unroll
            for (int reg = 0; reg < 4; ++reg) {
                int row = (wm * 4 + mi) * 16 + kq * 4 + reg;
                sm16[row * 136 + col] = f2bf(gelu_exact(acc[mi][ni][reg] + bb));
            }
    }
    __syncthreads();
    int trow = tid >> 1, thalf = tid & 1;
    const unsigned short* src = sm16 + trow * 136 + thalf * 64;
    unsigned short* dst = h_bf + (size_t)(m0 + trow) * HID_ + n0 + thalf * 64;
#pragma unroll
    for (int j = 0; j < 8; ++j)
        *(bf16x8*)(dst + j * 8) = *(const bf16x8*)(src + j * 8);
}

// ---------------- fc2 GEMM + LN + gamma2 residual + BN2 + x-residual + ReLU -> out (NCHW) ----------------
__global__ __launch_bounds__(256) void k_fc2fin_mfma(const unsigned short* __restrict__ h_bf,
                                                     const unsigned short* __restrict__ fc2wT,
                                                     const float* __restrict__ fc2b,
                                                     const float* __restrict__ g2, const float* __restrict__ lg,
                                                     const float* __restrict__ lb, const float* __restrict__ t,
                                                     const float* __restrict__ x,
                                                     const float* __restrict__ bn2g, const float* __restrict__ bn2b,
                                                     const float* __restrict__ bn2m, const float* __restrict__ bn2v,
                                                     float* __restrict__ out) {
    __shared__ __align__(16) unsigned char smem[81920];   // 2 x (A 8KB + B 32KB); reused as ot[64][257] f32
    unsigned short* sm16 = (unsigned short*)smem;
    int tid = threadIdx.x;
    int wave = tid >> 6, lane = tid & 63;
    int r = lane & 15, kq = lane >> 4;
    int m0 = blockIdx.x * 64;

    f32x4 acc[16] = {};

    auto stage = [&](int kt, int buf) {
        int k0 = kt * 64;
        unsigned short* dstA = sm16 + buf * 20480;
        unsigned short* dstB = dstA + 4096;
#pragma unroll
        for (int i = 0; i < 2; ++i) {
            int q = wave * 2 + i;
            int row = m0 + wave * 16 + r;
            GLOAD_LDS16(h_bf + (size_t)row * HID_ + k0 + (i * 4 + kq) * 8, dstA + q * 512);
        }
#pragma unroll
        for (int i = 0; i < 8; ++i) {
            int q = wave * 8 + i;
            int nrow = (q >> 1) * 16 + r;
            int cc   = (q & 1) * 4 + kq;
            GLOAD_LDS16(fc2wT + (size_t)nrow * HID_ + k0 + cc * 8, dstB + q * 512);
        }
    };

    stage(0, 0);
    int cur = 0;
#pragma unroll 1
    for (int kt = 0; kt < 16; ++kt) {
        if (kt < 15) {
            stage(kt + 1, cur ^ 1);
            asm volatile("s_waitcnt vmcnt(10)" ::: "memory");
        } else {
            asm volatile("s_waitcnt vmcnt(0)" ::: "memory");
        }
        __builtin_amdgcn_s_barrier();
        bf16x8* sA = (bf16x8*)(sm16 + cur * 20480);
        bf16x8* sB = sA + 512;
#pragma unroll
        for (int ks = 0; ks < 2; ++ks) {
            bf16x8 a = sA[(wave * 2 + ks) * 64 + lane];
#pragma unroll
            for (int ni = 0; ni < 16; ++ni) {
                bf16x8 b = sB[(ni * 2 + ks) * 64 + lane];
                acc[ni] = __builtin_amdgcn_mfma_f32_16x16x32_bf16(a, b, acc[ni], 0, 0, 0);
            }
        }
        __builtin_amdgcn_s_barrier();
        cur ^= 1;
    }

    // epilogue 1: bias, per-row LN (in-wave), gamma2 residual -> ot[64][257] in LDS
    float* ot = (float*)smem;
    float bb[16], g2v[16], lgv[16], lbv[16];
#pragma unroll
    for (int ni = 0; ni < 16; ++ni) {
        int col = ni * 16 + r;
        bb[ni] = fc2b[col]; g2v[ni] = g2[col]; lgv[ni] = lg[col]; lbv[ni] = lb[col];
    }
#pragma unroll
    for (int ni = 0; ni < 16; ++ni)
#pragma unroll
        for (int reg = 0; reg < 4; ++reg) acc[ni][reg] += bb[ni];
#pragma unroll
    for (int reg = 0; reg < 4; ++reg) {
        float s1 = 0.f, s2 = 0.f;
#pragma unroll
        for (int ni = 0; ni < 16; ++ni) { float vv = acc[ni][reg]; s1 += vv; s2 += vv * vv; }
#pragma unroll
        for (int off = 1; off < 16; off <<= 1) { s1 += __shfl_xor(s1, off, 64); s2 += __shfl_xor(s2, off, 64); }
        float mu  = s1 * (1.f / C_);
        float var = fmaxf(s2 * (1.f / C_) - mu * mu, 0.f);
        float rs  = rsqrtf(var + 1e-5f);
        int row_local = wave * 16 + kq * 4 + reg;
        const float* tr = t + (size_t)(m0 + row_local) * C_;
#pragma unroll
        for (int ni = 0; ni < 16; ++ni) {
            int col = ni * 16 + r;
            ot[row_local * 257 + col] = tr[col] + g2v[ni] * ((acc[ni][reg] - mu) * rs * lgv[ni] + lbv[ni]);
        }
    }
    __syncthreads();

    // epilogue 2: BN2 + x residual + ReLU, NCHW coalesced writes (lane = hw, per-channel 256B runs)
    int n  = m0 / HW_;
    int hw0 = m0 - n * HW_;
#pragma unroll 1
    for (int i = 0; i < 64; ++i) {
        int c = wave * 64 + i;                 // wave-uniform channel
        float sc = bn2g[c] * rsqrtf(bn2v[c] + 1e-5f);
        float sh = bn2b[c] - bn2m[c] * sc;
        size_t gidx = ((size_t)(n * C_ + c)) * HW_ + hw0 + lane;
        float val = ot[lane * 257 + c] * sc + sh + x[gidx];
        out[gidx] = fmaxf(val, 0.f);
    }
}

extern "C" void kernel_launch(void* const* d_in, const int* in_sizes, int n_in,
                              void* d_out, int out_size, void* d_ws, size_t ws_size,
                              hipStream_t stream) {
    const float* x      = (const float*)d_in[0];
    const float* conv1w = (const float*)d_in[1];
    const float* bn1g   = (const float*)d_in[2];
    const float* bn1b   = (const float*)d_in[3];
    const float* bn1m   = (const float*)d_in[4];
    const float* bn1v   = (const float*)d_in[5];
    const float* ln1g   = (const float*)d_in[6];
    const float* ln1b   = (const float*)d_in[7];
    const float* dww    = (const float*)d_in[8];
    const float* dwb    = (const float*)d_in[9];
    const float* dwlng  = (const float*)d_in[10];
    const float* dwlnb  = (const float*)d_in[11];
    const float* offw   = (const float*)d_in[12];
    const float* offb   = (const float*)d_in[13];
    const float* mskw   = (const float*)d_in[14];
    const float* mskb   = (const float*)d_in[15];
    const float* inpw   = (const float*)d_in[16];
    const float* inpb   = (const float*)d_in[17];
    const float* outpw  = (const float*)d_in[18];
    const float* outpb  = (const float*)d_in[19];
    const float* gamma1 = (const float*)d_in[20];
    const float* ln2g   = (const float*)d_in[21];
    const float* ln2b   = (const float*)d_in[22];
    const float* fc1w   = (const float*)d_in[23];
    const float* fc1b   = (const float*)d_in[24];
    const float* fc2w   = (const float*)d_in[25];
    const float* fc2b   = (const float*)d_in[26];
    const float* gamma2 = (const float*)d_in[27];
    const float* bn2g   = (const float*)d_in[28];
    const float* bn2b   = (const float*)d_in[29];
    const float* bn2m   = (const float*)d_in[30];
    const float* bn2v   = (const float*)d_in[31];
    float* out = (float*)d_out;

    // ---- workspace layout ----
    // Front region (51.4MB): h_bf for MLP, aliasing {xproj_bf, offo, msko, x1_bf} (all dead by fc1).
    unsigned short* h_bf     = (unsigned short*)d_ws;                        // [NHW][1024] bf16
    unsigned short* xproj_bf = (unsigned short*)d_ws;                        // [NHW][256] bf16
    float* offo  = (float*)(xproj_bf + (size_t)NHW_ * C_);                   // [NHW][144] f32
    float* msko  = offo + (size_t)NHW_ * 144;                                // [NHW][72]  f32
    unsigned short* x1_bf = (unsigned short*)(msko + (size_t)NHW_ * 72);     // [NHW][256] bf16
    // (front usage 47.3MB <= h_bf's 51.4MB)
    unsigned short* scr   = h_bf + (size_t)NHW_ * HID_;   // xpad / core_bf alias (13.78MB)
    float* t     = (float*)(scr + (size_t)N_ * XP_H * XP_W * C_);            // [NHW][256] f32
    float* omb   = t + (size_t)NHW_ * C_;                 // [256] f32
    unsigned short* t_bf  = (unsigned short*)(omb + 256); // [NHW][256]
    unsigned short* wTT   = t_bf  + (size_t)NHW_ * C_;    // [9][256][256]
    unsigned short* inpwT = wTT   + (size_t)9 * C_ * C_;  // [256][256]
    unsigned short* outpwT= inpwT + (size_t)C_ * C_;
    unsigned short* fc1wT = outpwT+ (size_t)C_ * C_;      // [1024][256]
    unsigned short* fc2wT = fc1wT + (size_t)HID_ * C_;    // [256][1024]
    unsigned short* omT   = fc2wT + (size_t)C_ * HID_;    // [256][256]
    unsigned short* xpad    = scr;
    unsigned short* core_bf = scr;

    hipMemsetAsync(xpad, 0, (size_t)N_ * XP_H * XP_W * C_ * sizeof(unsigned short), stream);
    k_prep_xpad<<<N_ * H_, 256, 0, stream>>>(x, xpad);
    k_prep_wTT <<<2304,    256, 0, stream>>>(conv1w, wTT);
    k_prep_sqT <<<256,     256, 0, stream>>>(inpw, inpwT);
    k_prep_sqT <<<256,     256, 0, stream>>>(outpw, outpwT);
    k_prep_fc1T<<<1024,    256, 0, stream>>>(fc1w, fc1wT);
    k_prep_fc2T<<<256,     256, 0, stream>>>(fc2w, fc2wT);
    k_prep_om  <<<256,     256, 0, stream>>>(offw, offb, mskw, mskb, omT, omb);

    k_conv1_mfma  <<<(NHW_ / 128) * 2, 256, 0, stream>>>(xpad, wTT, bn1g, bn1b, bn1m, bn1v, t, t_bf);
    k_inproj_mfma <<<NHW_ / 64, 256, 0, stream>>>(t_bf, inpwT, inpb, xproj_bf);
    k_dw          <<<NHW_ / 4,  256, 0, stream>>>(t_bf, dww, dwb, dwlng, dwlnb, x1_bf);
    k_offmask_mfma<<<NHW_ / 32, 256, 0, stream>>>(x1_bf, omT, omb, offo, msko);
    k_core        <<<NHW_ / 8,  256, 0, stream>>>(xproj_bf, offo, msko, core_bf);
    k_outproj_mfma<<<NHW_ / 32, 256, 0, stream>>>(core_bf, outpwT, outpb, gamma1, ln1g, ln1b, t, t_bf);
    k_fc1_mfma    <<<(NHW_ / 128) * 8, 256, 0, stream>>>(t_bf, fc1wT, fc1b, h_bf);
    k_fc2fin_mfma <<<NHW_ / 64, 256, 0, stream>>>(h_bf, fc2wT, fc2b, gamma2, ln2g, ln2b, t,
                                                  x, bn2g, bn2b, bn2m, bn2v, out);
}